// Round 1
// baseline (545.593 us; speedup 1.0000x reference)
//
#include <hip/hip_runtime.h>
#include <hip/hip_bf16.h>
#include <math.h>

typedef __bf16 bf16;
typedef __bf16 bf16x4 __attribute__((ext_vector_type(4)));
typedef __bf16 bf16x8 __attribute__((ext_vector_type(8)));
typedef float f32x4 __attribute__((ext_vector_type(4)));

#define B_   2
#define T_   2048
#define HID_ 2048
#define NH_  16
#define KVH_ 4
#define HD_  128

// ---------------- cast fp32 -> bf16 (vectorized) ----------------
__global__ void cast_to_bf16(const float* __restrict__ in, bf16* __restrict__ out, int n4) {
    int i = blockIdx.x * 256 + threadIdx.x;
    if (i < n4) {
        float4 v = ((const float4*)in)[i];
        bf16x4 o = { (bf16)v.x, (bf16)v.y, (bf16)v.z, (bf16)v.w };
        ((bf16x4*)out)[i] = o;
    }
}

// ---------------- transpose + cast: in (K x N) fp32 -> out rows [rowOff..rowOff+N) (N x K) bf16
__global__ void transpose_cast(const float* __restrict__ in, bf16* __restrict__ out,
                               int N, int rowOff, int outStride) {
    __shared__ float tile[32][33];
    int k0 = blockIdx.x * 32, n0 = blockIdx.y * 32;
    int tx = threadIdx.x & 31, ty = threadIdx.x >> 5;
    for (int i = ty; i < 32; i += 8)
        tile[i][tx] = in[(size_t)(k0 + i) * N + n0 + tx];
    __syncthreads();
    for (int i = ty; i < 32; i += 8)
        out[(size_t)(rowOff + n0 + i) * outStride + (k0 + tx)] = (bf16)tile[tx][i];
}

// ---------------- bf16 MFMA GEMM: C(MxN) = A(MxK) @ BT(NxK)^T, fp32 out ----------------
// 128x128 block tile, 4 waves in 2x2, each wave 64x64 = 4x4 MFMA tiles (16x16x32).
__global__ __launch_bounds__(256, 2) void gemm_bf16_nt(
    const bf16* __restrict__ A, const bf16* __restrict__ BT, float* __restrict__ C,
    int M, int N, int K) {
    __shared__ __align__(16) bf16 As[128][40]; // +8 pad keeps 16B row alignment, ~2-way banks
    __shared__ __align__(16) bf16 Bs[128][40];
    int bm = blockIdx.x * 128, bn = blockIdx.y * 128;
    int tid = threadIdx.x, lane = tid & 63, wave = tid >> 6;
    int wm = (wave & 1) * 64, wn = (wave >> 1) * 64;
    int lm = lane & 15, quad = lane >> 4, kq = quad * 8;
    f32x4 acc[4][4] = {};
    int lrow = tid >> 1, lch = (tid & 1) * 16;
    const bf16* aptr = A  + (size_t)(bm + lrow) * K + lch;
    const bf16* bptr = BT + (size_t)(bn + lrow) * K + lch;
    for (int k0 = 0; k0 < K; k0 += 32) {
        *(bf16x8*)&As[lrow][lch]     = *(const bf16x8*)(aptr);
        *(bf16x8*)&As[lrow][lch + 8] = *(const bf16x8*)(aptr + 8);
        *(bf16x8*)&Bs[lrow][lch]     = *(const bf16x8*)(bptr);
        *(bf16x8*)&Bs[lrow][lch + 8] = *(const bf16x8*)(bptr + 8);
        aptr += 32; bptr += 32;
        __syncthreads();
        bf16x8 af[4], bfr[4];
        #pragma unroll
        for (int mt = 0; mt < 4; mt++) af[mt]  = *(const bf16x8*)&As[wm + mt*16 + lm][kq];
        #pragma unroll
        for (int nt = 0; nt < 4; nt++) bfr[nt] = *(const bf16x8*)&Bs[wn + nt*16 + lm][kq];
        #pragma unroll
        for (int mt = 0; mt < 4; mt++)
            #pragma unroll
            for (int nt = 0; nt < 4; nt++)
                acc[mt][nt] = __builtin_amdgcn_mfma_f32_16x16x32_bf16(af[mt], bfr[nt], acc[mt][nt], 0, 0, 0);
        __syncthreads();
    }
    #pragma unroll
    for (int mt = 0; mt < 4; mt++) {
        #pragma unroll
        for (int r = 0; r < 4; r++) {
            int row = bm + wm + mt*16 + quad*4 + r;
            float* cp = C + (size_t)row * N + bn + wn + lm;
            #pragma unroll
            for (int nt = 0; nt < 4; nt++)
                cp[nt*16] = acc[mt][nt][r];
        }
    }
}

// ---------------- RoPE + scatter to head-major bf16 (Q scaled by 1/sqrt(HD), V transposed) ---
__global__ void rope_scatter(const float* __restrict__ qkv,
                             const float* __restrict__ cosb, const float* __restrict__ sinb,
                             bf16* __restrict__ q, bf16* __restrict__ k, bf16* __restrict__ vT) {
    int bt = blockIdx.x;
    int b = bt >> 11, t = bt & 2047;
    const float* row = qkv + (size_t)bt * 3072;
    for (int col = threadIdx.x; col < 3072; col += 256) {
        float v = row[col];
        if (col < 2048) {
            int h = col >> 7, d = col & 127;
            float c = cosb[t*128 + d], s = sinb[t*128 + d];
            float rot = (d < 64) ? -row[col + 64] : row[col - 64];
            float val = (v * c + rot * s) * 0.08838834764831843f; // 1/sqrt(128)
            q[((size_t)(b*NH_ + h) * T_ + t) * HD_ + d] = (bf16)val;
        } else if (col < 2560) {
            int idx = col - 2048, h = idx >> 7, d = idx & 127;
            float c = cosb[t*128 + d], s = sinb[t*128 + d];
            float rot = (d < 64) ? -row[col + 64] : row[col - 64];
            k[((size_t)(b*KVH_ + h) * T_ + t) * HD_ + d] = (bf16)(v * c + rot * s);
        } else {
            int idx = col - 2560, h = idx >> 7, d = idx & 127;
            vT[((size_t)(b*KVH_ + h) * HD_ + d) * T_ + t] = (bf16)v;
        }
    }
}

// ---------------- flash attention (causal, online softmax) ----------------
// grid: (T/64, B*NH). 4 waves/block, each wave owns 16 q-rows. Bc=32 kv-tile in LDS.
__global__ __launch_bounds__(256, 2) void flash_attn(
    const bf16* __restrict__ q, const bf16* __restrict__ k, const bf16* __restrict__ vT,
    bf16* __restrict__ ctx) {
    __shared__ __align__(16) bf16 Ks[32][136];    // K tile (s,d), +8 pad
    __shared__ __align__(16) bf16 Vt[128][40];    // V^T tile (d,s), +8 pad
    __shared__ __align__(16) bf16 Ps[4][16][40];  // per-wave P transpose buffer
    int qb = blockIdx.x * 64;
    int bh = blockIdx.y;
    int b = bh >> 4, h = bh & 15, kvh = h >> 2;
    int tid = threadIdx.x, lane = tid & 63, w = tid >> 6;
    int lm = lane & 15, quad = lane >> 4, kq = quad * 8;

    int qrow = qb + w * 16 + lm;
    const bf16* qg = q + ((size_t)(b * NH_ + h) * T_ + qrow) * HD_;
    bf16x8 qf[4];
    #pragma unroll
    for (int kk = 0; kk < 4; kk++) qf[kk] = *(const bf16x8*)(qg + kk*32 + kq);

    f32x4 O[8] = {};
    float m_i[4] = {-1e30f, -1e30f, -1e30f, -1e30f};
    float l_i[4] = {0.f, 0.f, 0.f, 0.f};

    const bf16* kg = k  + (size_t)(b * KVH_ + kvh) * T_ * HD_;
    const bf16* vg = vT + (size_t)(b * KVH_ + kvh) * HD_ * T_;
    int kend = qb + 64;
    int srow = tid >> 3, sseg = (tid & 7) * 16;  // K staging 32x128
    int vrow = tid >> 1, vseg = (tid & 1) * 16;  // V staging 128x32

    for (int s0 = 0; s0 < kend; s0 += 32) {
        const bf16* ksrc = kg + (size_t)(s0 + srow) * HD_ + sseg;
        *(bf16x8*)&Ks[srow][sseg]     = *(const bf16x8*)(ksrc);
        *(bf16x8*)&Ks[srow][sseg + 8] = *(const bf16x8*)(ksrc + 8);
        const bf16* vsrc = vg + (size_t)vrow * T_ + s0 + vseg;
        *(bf16x8*)&Vt[vrow][vseg]     = *(const bf16x8*)(vsrc);
        *(bf16x8*)&Vt[vrow][vseg + 8] = *(const bf16x8*)(vsrc + 8);
        __syncthreads();

        // S = Q @ K^T : 16x32 per wave
        f32x4 sacc[2] = {};
        #pragma unroll
        for (int nt = 0; nt < 2; nt++)
            #pragma unroll
            for (int kk = 0; kk < 4; kk++) {
                bf16x8 kf = *(const bf16x8*)&Ks[nt*16 + lm][kk*32 + kq];
                sacc[nt] = __builtin_amdgcn_mfma_f32_16x16x32_bf16(qf[kk], kf, sacc[nt], 0, 0, 0);
            }

        int myrow = qb + w*16 + quad*4;
        #pragma unroll
        for (int r = 0; r < 4; r++) {
            int rowg = myrow + r;
            float v0 = sacc[0][r]; if (s0 + lm       > rowg) v0 = -1e30f;
            float v1 = sacc[1][r]; if (s0 + 16 + lm  > rowg) v1 = -1e30f;
            float mx = fmaxf(v0, v1);
            #pragma unroll
            for (int off = 8; off >= 1; off >>= 1) mx = fmaxf(mx, __shfl_xor(mx, off));
            float mnew = fmaxf(m_i[r], mx);
            float p0 = __expf(v0 - mnew), p1 = __expf(v1 - mnew);
            float rs = p0 + p1;
            #pragma unroll
            for (int off = 8; off >= 1; off >>= 1) rs += __shfl_xor(rs, off);
            float alpha = __expf(m_i[r] - mnew);
            l_i[r] = l_i[r] * alpha + rs;
            m_i[r] = mnew;
            #pragma unroll
            for (int dt = 0; dt < 8; dt++) O[dt][r] *= alpha;
            Ps[w][quad*4 + r][lm]      = (bf16)p0;
            Ps[w][quad*4 + r][16 + lm] = (bf16)p1;
        }
        __syncthreads();  // P ready (also fences Ks reads before next stage)

        // O += P @ V : P(16x32) A-frag, V^T rows give contiguous B-frags
        bf16x8 pf = *(const bf16x8*)&Ps[w][lm][kq];
        #pragma unroll
        for (int dt = 0; dt < 8; dt++) {
            bf16x8 vf = *(const bf16x8*)&Vt[dt*16 + lm][kq];
            O[dt] = __builtin_amdgcn_mfma_f32_16x16x32_bf16(pf, vf, O[dt], 0, 0, 0);
        }
        __syncthreads();  // Vt/Ps reads done before next stage
    }

    int b_t = b * T_;
    #pragma unroll
    for (int r = 0; r < 4; r++) {
        int rowg = qb + w*16 + quad*4 + r;
        float inv = 1.0f / l_i[r];
        bf16* cp = ctx + (size_t)(b_t + rowg) * HID_ + h * HD_ + lm;
        #pragma unroll
        for (int dt = 0; dt < 8; dt++)
            cp[dt*16] = (bf16)(O[dt][r] * inv);
    }
}

extern "C" void kernel_launch(void* const* d_in, const int* in_sizes, int n_in,
                              void* d_out, int out_size, void* d_ws, size_t ws_size,
                              hipStream_t stream) {
    const float* hidden = (const float*)d_in[0];
    // d_in[1] attention_mask: pure causal -1e9 — applied analytically in flash_attn
    const float* cosb = (const float*)d_in[2];
    const float* sinb = (const float*)d_in[3];
    const float* Wq = (const float*)d_in[4];
    const float* Wk = (const float*)d_in[5];
    const float* Wv = (const float*)d_in[6];
    const float* Wo = (const float*)d_in[7];
    float* out = (float*)d_out;

    char* ws = (char*)d_ws;
    size_t off = 0;
    bf16* hid_bf = (bf16*)(ws + off); off += (size_t)4096*2048*2;   // 16.8 MB
    bf16* WqkvT  = (bf16*)(ws + off); off += (size_t)3072*2048*2;   // 12.6 MB
    bf16* WoT    = (bf16*)(ws + off); off += (size_t)2048*2048*2;   // 8.4 MB
    float* QKV   = (float*)(ws + off); off += (size_t)4096*3072*4;  // 50.3 MB
    bf16* qbuf   = (bf16*)(ws + off); off += (size_t)B_*NH_*T_*HD_*2;   // 16.8 MB
    bf16* kbuf   = (bf16*)(ws + off); off += (size_t)B_*KVH_*T_*HD_*2;  // 4.2 MB
    bf16* vtbuf  = (bf16*)(ws + off); off += (size_t)B_*KVH_*HD_*T_*2;  // 4.2 MB
    bf16* ctx    = (bf16*)(ws + off); off += (size_t)4096*2048*2;   // 16.8 MB

    cast_to_bf16<<<8192, 256, 0, stream>>>(hidden, hid_bf, 4096*2048/4);
    transpose_cast<<<dim3(64, 64), 256, 0, stream>>>(Wq, WqkvT, 2048, 0,    2048);
    transpose_cast<<<dim3(64, 16), 256, 0, stream>>>(Wk, WqkvT, 512,  2048, 2048);
    transpose_cast<<<dim3(64, 16), 256, 0, stream>>>(Wv, WqkvT, 512,  2560, 2048);
    transpose_cast<<<dim3(64, 64), 256, 0, stream>>>(Wo, WoT,   2048, 0,    2048);

    gemm_bf16_nt<<<dim3(32, 24), 256, 0, stream>>>(hid_bf, WqkvT, QKV, 4096, 3072, 2048);
    rope_scatter<<<4096, 256, 0, stream>>>(QKV, cosb, sinb, qbuf, kbuf, vtbuf);
    flash_attn<<<dim3(32, 32), 256, 0, stream>>>(qbuf, kbuf, vtbuf, ctx);
    gemm_bf16_nt<<<dim3(32, 16), 256, 0, stream>>>(ctx, WoT, out, 4096, 2048, 2048);
}

// Round 2
// 389.619 us; speedup vs baseline: 1.4003x; 1.4003x over previous
//
#include <hip/hip_runtime.h>
#include <hip/hip_bf16.h>
#include <math.h>

typedef __bf16 bf16;
typedef __bf16 bf16x4 __attribute__((ext_vector_type(4)));
typedef __bf16 bf16x8 __attribute__((ext_vector_type(8)));
typedef float f32x4 __attribute__((ext_vector_type(4)));

#define B_   2
#define T_   2048
#define HID_ 2048
#define NH_  16
#define KVH_ 4
#define HD_  128

__device__ __forceinline__ void gload_lds16(const bf16* g, bf16* l) {
    __builtin_amdgcn_global_load_lds(
        (const __attribute__((address_space(1))) unsigned int*)g,
        (__attribute__((address_space(3))) unsigned int*)l, 16, 0, 0);
}

// ---------------- cast fp32 -> bf16 (vectorized) ----------------
__global__ void cast_to_bf16(const float* __restrict__ in, bf16* __restrict__ out, int n4) {
    int i = blockIdx.x * 256 + threadIdx.x;
    if (i < n4) {
        float4 v = ((const float4*)in)[i];
        bf16x4 o = { (bf16)v.x, (bf16)v.y, (bf16)v.z, (bf16)v.w };
        ((bf16x4*)out)[i] = o;
    }
}

// ---------------- transpose + cast: in (K x N) fp32 -> out rows [rowOff..rowOff+N) (N x K) bf16
__global__ void transpose_cast(const float* __restrict__ in, bf16* __restrict__ out,
                               int N, int rowOff, int outStride) {
    __shared__ float tile[32][33];
    int k0 = blockIdx.x * 32, n0 = blockIdx.y * 32;
    int tx = threadIdx.x & 31, ty = threadIdx.x >> 5;
    for (int i = ty; i < 32; i += 8)
        tile[i][tx] = in[(size_t)(k0 + i) * N + n0 + tx];
    __syncthreads();
    for (int i = ty; i < 32; i += 8)
        out[(size_t)(rowOff + n0 + i) * outStride + (k0 + tx)] = (bf16)tile[tx][i];
}

// ---------------- bf16 MFMA GEMM: C(MxN) = A(MxK) @ BT(NxK)^T, fp32 out ----------------
// m97 structure: 128x128 tile, BK=32, global_load_lds width-16 staging into unpadded LDS,
// 16B segments XOR-swizzled by (row&3) to break the 64B-row bank aliasing.
__global__ __launch_bounds__(256, 2) void gemm_bf16_nt(
    const bf16* __restrict__ A, const bf16* __restrict__ BT, float* __restrict__ C,
    int M, int N, int K) {
    __shared__ __align__(16) bf16 As[128 * 32];
    __shared__ __align__(16) bf16 Bs[128 * 32];
    int bm = blockIdx.x * 128, bn = blockIdx.y * 128;
    int tid = threadIdx.x, lane = tid & 63, w = tid >> 6;
    int wm = (w & 1) * 64, wn = (w >> 1) * 64;
    int lm = lane & 15, quad = lane >> 4;
    // staging: 512 16B-chunks per tile; this lane covers chunks c0 (j=0) and c1 (j=1).
    // chunk c -> LDS row c>>2, lds seg c&3; global seg = (c&3) ^ (row&3)  (XOR swizzle)
    int c0 = w * 64 + lane, c1 = 256 + c0;
    int r0 = c0 >> 2, g0 = ((c0 & 3) ^ (r0 & 3)) * 8;
    int r1 = c1 >> 2, g1 = ((c1 & 3) ^ (r1 & 3)) * 8;
    const bf16* a0 = A  + (size_t)(bm + r0) * K + g0;
    const bf16* a1 = A  + (size_t)(bm + r1) * K + g1;
    const bf16* b0 = BT + (size_t)(bn + r0) * K + g0;
    const bf16* b1 = BT + (size_t)(bn + r1) * K + g1;
    bf16* lA0 = As + (size_t)(w * 64) * 8;        // wave-uniform LDS bases (HW adds lane*16B)
    bf16* lA1 = As + (size_t)(256 + w * 64) * 8;
    bf16* lB0 = Bs + (size_t)(w * 64) * 8;
    bf16* lB1 = Bs + (size_t)(256 + w * 64) * 8;
    int sx = ((quad ^ (lm & 3)) << 3);            // swizzled seg offset for frag reads
    f32x4 acc[4][4] = {};
    for (int k0 = 0; k0 < K; k0 += 32) {
        gload_lds16(a0, lA0); gload_lds16(a1, lA1);
        gload_lds16(b0, lB0); gload_lds16(b1, lB1);
        a0 += 32; a1 += 32; b0 += 32; b1 += 32;
        __syncthreads();
        bf16x8 af[4], bfr[4];
        #pragma unroll
        for (int mt = 0; mt < 4; mt++) af[mt]  = *(const bf16x8*)&As[(wm + mt*16 + lm) * 32 + sx];
        #pragma unroll
        for (int nt = 0; nt < 4; nt++) bfr[nt] = *(const bf16x8*)&Bs[(wn + nt*16 + lm) * 32 + sx];
        #pragma unroll
        for (int mt = 0; mt < 4; mt++)
            #pragma unroll
            for (int nt = 0; nt < 4; nt++)
                acc[mt][nt] = __builtin_amdgcn_mfma_f32_16x16x32_bf16(af[mt], bfr[nt], acc[mt][nt], 0, 0, 0);
        __syncthreads();
    }
    #pragma unroll
    for (int mt = 0; mt < 4; mt++) {
        #pragma unroll
        for (int r = 0; r < 4; r++) {
            int row = bm + wm + mt*16 + quad*4 + r;
            float* cp = C + (size_t)row * N + bn + wn + lm;
            #pragma unroll
            for (int nt = 0; nt < 4; nt++)
                cp[nt*16] = acc[mt][nt][r];
        }
    }
}

// ---------------- RoPE + scatter to head-major bf16 (Q scaled by 1/sqrt(HD), V transposed) ---
__global__ void rope_scatter(const float* __restrict__ qkv,
                             const float* __restrict__ cosb, const float* __restrict__ sinb,
                             bf16* __restrict__ q, bf16* __restrict__ k, bf16* __restrict__ vT) {
    int bt = blockIdx.x;
    int b = bt >> 11, t = bt & 2047;
    const float* row = qkv + (size_t)bt * 3072;
    for (int col = threadIdx.x; col < 3072; col += 256) {
        float v = row[col];
        if (col < 2048) {
            int h = col >> 7, d = col & 127;
            float c = cosb[t*128 + d], s = sinb[t*128 + d];
            float rot = (d < 64) ? -row[col + 64] : row[col - 64];
            float val = (v * c + rot * s) * 0.08838834764831843f; // 1/sqrt(128)
            q[((size_t)(b*NH_ + h) * T_ + t) * HD_ + d] = (bf16)val;
        } else if (col < 2560) {
            int idx = col - 2048, h = idx >> 7, d = idx & 127;
            float c = cosb[t*128 + d], s = sinb[t*128 + d];
            float rot = (d < 64) ? -row[col + 64] : row[col - 64];
            k[((size_t)(b*KVH_ + h) * T_ + t) * HD_ + d] = (bf16)(v * c + rot * s);
        } else {
            int idx = col - 2560, h = idx >> 7, d = idx & 127;
            vT[((size_t)(b*KVH_ + h) * HD_ + d) * T_ + t] = (bf16)v;
        }
    }
}

// ---------------- flash attention (causal, online softmax, O^T form) ----------------
// grid: (16, B*NH). Block handles q-tiles bx and 31-bx (64 rows each) -> every block
// does exactly 33 KV iterations of Bc=64 (perfect causal load balance).
// PV computes O^T = V^T @ P^T (A=V^T frag, B=P frag): per-lane q-row = lm, so the
// online-softmax rescale is a wave-local broadcast and O stores are packed bf16x4.
__global__ __launch_bounds__(256, 2) void flash_attn(
    const bf16* __restrict__ q, const bf16* __restrict__ k, const bf16* __restrict__ vT,
    bf16* __restrict__ ctx) {
    __shared__ __align__(16) bf16 Ks[64][136];    // K tile (s,d), +8 pad
    __shared__ __align__(16) bf16 Vt[128][72];    // V^T tile (d,s), +8 pad
    __shared__ __align__(16) bf16 Ps[4][16][72];  // per-wave P (row=q, col=s)
    __shared__ float alpha_s[4][16];
    __shared__ float l_s[4][16];
    int bh = blockIdx.y;
    int b = bh >> 4, h = bh & 15, kvh = h >> 2;
    int tid = threadIdx.x, lane = tid & 63, w = tid >> 6;
    int lm = lane & 15, quad = lane >> 4, kq = quad * 8;
    const bf16* kg = k  + (size_t)(b * KVH_ + kvh) * T_ * HD_;
    const bf16* vg = vT + (size_t)(b * KVH_ + kvh) * HD_ * T_;
    int krow = tid >> 2, kcol = (tid & 3) * 32;   // K staging: 64x128
    int vrow = tid >> 1, vcol = (tid & 1) * 32;   // V staging: 128x64

    for (int half = 0; half < 2; half++) {
        int qt = (half == 0) ? blockIdx.x : (31 - blockIdx.x);
        int qrow = qt * 64 + w * 16 + lm;
        const bf16* qg = q + ((size_t)(b * NH_ + h) * T_ + qrow) * HD_;
        bf16x8 qf[4];
        #pragma unroll
        for (int kk = 0; kk < 4; kk++) qf[kk] = *(const bf16x8*)(qg + kk*32 + kq);

        f32x4 Ot[8] = {};
        float m_i[4] = {-1e30f, -1e30f, -1e30f, -1e30f};
        float l_i[4] = {0.f, 0.f, 0.f, 0.f};
        int nIter = qt + 1;

        for (int it = 0; it < nIter; it++) {
            int s0 = it * 64;
            {   // stage K (64x128) and V^T (128x64)
                const bf16* ksrc = kg + (size_t)(s0 + krow) * HD_ + kcol;
                #pragma unroll
                for (int j = 0; j < 4; j++)
                    *(bf16x8*)&Ks[krow][kcol + j*8] = *(const bf16x8*)(ksrc + j*8);
                const bf16* vsrc = vg + (size_t)vrow * T_ + s0 + vcol;
                #pragma unroll
                for (int j = 0; j < 4; j++)
                    *(bf16x8*)&Vt[vrow][vcol + j*8] = *(const bf16x8*)(vsrc + j*8);
            }
            __syncthreads();

            // S = Q @ K^T : 16x64 per wave (C-layout: row q = quad*4+r, col s = nt*16+lm)
            f32x4 sacc[4] = {};
            #pragma unroll
            for (int nt = 0; nt < 4; nt++)
                #pragma unroll
                for (int kk = 0; kk < 4; kk++) {
                    bf16x8 kf = *(const bf16x8*)&Ks[nt*16 + lm][kk*32 + kq];
                    sacc[nt] = __builtin_amdgcn_mfma_f32_16x16x32_bf16(qf[kk], kf, sacc[nt], 0, 0, 0);
                }

            bool diag = (it == nIter - 1);  // only the diagonal tile needs masking
            #pragma unroll
            for (int r = 0; r < 4; r++) {
                int rloc = w*16 + quad*4 + r;  // row within 64-row q-tile
                float v0 = sacc[0][r], v1 = sacc[1][r], v2 = sacc[2][r], v3 = sacc[3][r];
                if (diag) {
                    if (     lm > rloc) v0 = -1e30f;
                    if (16 + lm > rloc) v1 = -1e30f;
                    if (32 + lm > rloc) v2 = -1e30f;
                    if (48 + lm > rloc) v3 = -1e30f;
                }
                float mx = fmaxf(fmaxf(v0, v1), fmaxf(v2, v3));
                #pragma unroll
                for (int off = 8; off >= 1; off >>= 1) mx = fmaxf(mx, __shfl_xor(mx, off));
                float mnew = fmaxf(m_i[r], mx);
                float p0 = __expf(v0 - mnew), p1 = __expf(v1 - mnew);
                float p2 = __expf(v2 - mnew), p3 = __expf(v3 - mnew);
                float rs = (p0 + p1) + (p2 + p3);
                #pragma unroll
                for (int off = 8; off >= 1; off >>= 1) rs += __shfl_xor(rs, off);
                float al = __expf(m_i[r] - mnew);
                l_i[r] = l_i[r] * al + rs;
                m_i[r] = mnew;
                Ps[w][quad*4 + r][     lm] = (bf16)p0;
                Ps[w][quad*4 + r][16 + lm] = (bf16)p1;
                Ps[w][quad*4 + r][32 + lm] = (bf16)p2;
                Ps[w][quad*4 + r][48 + lm] = (bf16)p3;
                if (lm == 0) alpha_s[w][quad*4 + r] = al;
            }
            // wave-local LDS round trip (no block barrier needed)
            float al2 = alpha_s[w][lm];
            #pragma unroll
            for (int dt = 0; dt < 8; dt++) Ot[dt] *= al2;

            // O^T += V^T @ P^T : A = V^T frag (m=d), B = P frag (n=q-row)
            #pragma unroll
            for (int kk2 = 0; kk2 < 2; kk2++) {
                bf16x8 pf = *(const bf16x8*)&Ps[w][lm][kk2*32 + kq];
                #pragma unroll
                for (int dt = 0; dt < 8; dt++) {
                    bf16x8 vf = *(const bf16x8*)&Vt[dt*16 + lm][kk2*32 + kq];
                    Ot[dt] = __builtin_amdgcn_mfma_f32_16x16x32_bf16(vf, pf, Ot[dt], 0, 0, 0);
                }
            }
            __syncthreads();  // all Ks/Vt reads done before next stage
        }

        #pragma unroll
        for (int r = 0; r < 4; r++)
            if (lm == 0) l_s[w][quad*4 + r] = l_i[r];
        float linv = 1.0f / l_s[w][lm];
        int token = qt*64 + w*16 + lm;
        bf16* cp = ctx + ((size_t)(b * T_) + token) * HID_ + h * HD_;
        #pragma unroll
        for (int dt = 0; dt < 8; dt++) {
            bf16x4 o4 = { (bf16)(Ot[dt][0] * linv), (bf16)(Ot[dt][1] * linv),
                          (bf16)(Ot[dt][2] * linv), (bf16)(Ot[dt][3] * linv) };
            *(bf16x4*)(cp + dt*16 + quad*4) = o4;
        }
    }
}

extern "C" void kernel_launch(void* const* d_in, const int* in_sizes, int n_in,
                              void* d_out, int out_size, void* d_ws, size_t ws_size,
                              hipStream_t stream) {
    const float* hidden = (const float*)d_in[0];
    // d_in[1] attention_mask: pure causal -1e9 — applied analytically in flash_attn
    const float* cosb = (const float*)d_in[2];
    const float* sinb = (const float*)d_in[3];
    const float* Wq = (const float*)d_in[4];
    const float* Wk = (const float*)d_in[5];
    const float* Wv = (const float*)d_in[6];
    const float* Wo = (const float*)d_in[7];
    float* out = (float*)d_out;

    char* ws = (char*)d_ws;
    size_t off = 0;
    bf16* hid_bf = (bf16*)(ws + off); off += (size_t)4096*2048*2;   // 16.8 MB
    bf16* WqkvT  = (bf16*)(ws + off); off += (size_t)3072*2048*2;   // 12.6 MB
    bf16* WoT    = (bf16*)(ws + off); off += (size_t)2048*2048*2;   // 8.4 MB
    float* QKV   = (float*)(ws + off); off += (size_t)4096*3072*4;  // 50.3 MB
    bf16* qbuf   = (bf16*)(ws + off); off += (size_t)B_*NH_*T_*HD_*2;   // 16.8 MB
    bf16* kbuf   = (bf16*)(ws + off); off += (size_t)B_*KVH_*T_*HD_*2;  // 4.2 MB
    bf16* vtbuf  = (bf16*)(ws + off); off += (size_t)B_*KVH_*HD_*T_*2;  // 4.2 MB
    bf16* ctx    = (bf16*)(ws + off); off += (size_t)4096*2048*2;   // 16.8 MB

    cast_to_bf16<<<8192, 256, 0, stream>>>(hidden, hid_bf, 4096*2048/4);
    transpose_cast<<<dim3(64, 64), 256, 0, stream>>>(Wq, WqkvT, 2048, 0,    2048);
    transpose_cast<<<dim3(64, 16), 256, 0, stream>>>(Wk, WqkvT, 512,  2048, 2048);
    transpose_cast<<<dim3(64, 16), 256, 0, stream>>>(Wv, WqkvT, 512,  2560, 2048);
    transpose_cast<<<dim3(64, 64), 256, 0, stream>>>(Wo, WoT,   2048, 0,    2048);

    gemm_bf16_nt<<<dim3(32, 24), 256, 0, stream>>>(hid_bf, WqkvT, QKV, 4096, 3072, 2048);
    rope_scatter<<<4096, 256, 0, stream>>>(QKV, cosb, sinb, qbuf, kbuf, vtbuf);
    flash_attn<<<dim3(16, 32), 256, 0, stream>>>(qbuf, kbuf, vtbuf, ctx);
    gemm_bf16_nt<<<dim3(32, 16), 256, 0, stream>>>(ctx, WoT, out, 4096, 2048, 2048);
}